// Round 1
// baseline (5597.081 us; speedup 1.0000x reference)
//
#include <hip/hip_runtime.h>
#include <hip/hip_bf16.h>
#include <stdint.h>

typedef __attribute__((ext_vector_type(8))) short bf16x8;
typedef __attribute__((ext_vector_type(4))) float f32x4;

// ---- problem constants ----
#define N_SAMP 128
#define T_STEPS 512

// ---- ws layout (bytes) ----
// wt (bf16): stage0 768x512, stage1 768x768, stage2 768x1024, layout [col][k], gate-cols permuted
#define WT_OFF    0u
#define GC_OFF    3538944u   // 768*(512+768+1024)*2
#define RING_OFF  4718592u   // GC + 3*128*768*4
// ring (bf16): [stage][slot(4)][128][256] -> 786432 B; total ws use 5505024 B

__device__ __forceinline__ ushort f2bf(float f) {
    uint32_t u = __float_as_uint(f);
    uint32_t r = u + 0x7FFFu + ((u >> 16) & 1u);
    return (ushort)(r >> 16);
}
__device__ __forceinline__ float sigmoidf_(float x) { return 1.0f / (1.0f + __expf(-x)); }

// ---------------- phase 0a: weight prep (fp32 -> bf16, transpose to [col][k], permute gate cols)
// permuted col c: b=c/96 (h-dim block of 32), cc=c%96, g=cc/32 (r/z/n), d32=cc%32 ; src row j=g*256+b*32+d32
// k<256 -> src col k (char part); k>=256 -> src col 512+k (h parts, original cols 768..)
__global__ void k_prep(const float* __restrict__ w0, const float* __restrict__ w1,
                       const float* __restrict__ w2, ushort* __restrict__ wt) {
    int idx = blockIdx.x * 256 + threadIdx.x;
    if (idx >= 1769472) return;
    int e, Ks, cols; const float* W;
    if (idx < 393216)      { e = idx;          Ks = 512;  cols = 1024; W = w0; }
    else if (idx < 983040) { e = idx - 393216; Ks = 768;  cols = 1280; W = w1; }
    else                   { e = idx - 983040; Ks = 1024; cols = 1536; W = w2; }
    int c = e / Ks, k = e % Ks;
    int b = c / 96, cc = c % 96, g = cc >> 5, d32 = cc & 31;
    int j = g * 256 + b * 32 + d32;
    int scol = (k < 256) ? k : (512 + k);
    wt[idx] = f2bf(W[(size_t)j * cols + scol]);
}

// ---------------- phase 0b: gconst[s][n][c] = bih[j] + (g<2? bhh[j]:0) + [sent,ctx] . Wih[j][256:768]
__global__ void k_gconst(const float* __restrict__ w0, const float* __restrict__ w1, const float* __restrict__ w2,
                         const float* __restrict__ bih0, const float* __restrict__ bih1, const float* __restrict__ bih2,
                         const float* __restrict__ bhh0, const float* __restrict__ bhh1, const float* __restrict__ bhh2,
                         const float* __restrict__ sent, const float* __restrict__ ctx,
                         float* __restrict__ gc) {
    int idx = blockIdx.x * 256 + threadIdx.x;   // ((s*768 + c)*128 + n)
    if (idx >= 3 * 768 * 128) return;
    int n = idx & 127;
    int scc = idx >> 7;
    int c = scc % 768, s = scc / 768;
    const float* W   = (s == 0) ? w0 : ((s == 1) ? w1 : w2);
    const float* bih = (s == 0) ? bih0 : ((s == 1) ? bih1 : bih2);
    const float* bhh = (s == 0) ? bhh0 : ((s == 1) ? bhh1 : bhh2);
    int cols = 1024 + 256 * s;
    int b = c / 96, cc = c % 96, g = cc >> 5, d32 = cc & 31;
    int j = g * 256 + b * 32 + d32;
    float acc = bih[j] + ((g < 2) ? bhh[j] : 0.0f);
    const float4* wr4 = (const float4*)(W + (size_t)j * cols + 256);
    const float4* sn4 = (const float4*)(sent + (size_t)n * 256);
    const float4* cx4 = (const float4*)(ctx + (size_t)n * 256);
    #pragma unroll 4
    for (int k = 0; k < 64; k++) {
        float4 wv = wr4[k], sv = sn4[k];
        acc += wv.x * sv.x + wv.y * sv.y + wv.z * sv.z + wv.w * sv.w;
    }
    #pragma unroll 4
    for (int k = 0; k < 64; k++) {
        float4 wv = wr4[64 + k], cv = cx4[k];
        acc += wv.x * cv.x + wv.y * cv.y + wv.z * cv.z + wv.w * cv.w;
    }
    gc[(size_t)(s * 128 + n) * 768 + c] = acc;
}

// ---------------- main pipelined step kernel
// launch i: stage s computes t = i - s. Grid 192 = 3 stages * 8 m-tiles(16 samples) * 8 n-blocks(32 h-dims)
// WG 128 threads (2 waves). A[16 x Ks] staged in LDS in MFMA fragment layout; B streamed from bf16 wt.
__global__ void __launch_bounds__(128) k_step(
    const float* __restrict__ chars, const ushort* __restrict__ wt,
    const float* __restrict__ gc, ushort* __restrict__ ring,
    const float* __restrict__ bhh0, const float* __restrict__ bhh1, const float* __restrict__ bhh2,
    const float* __restrict__ hw0, const float* __restrict__ hw1, const float* __restrict__ hw2,
    const float* __restrict__ hb0, const float* __restrict__ hb1, const float* __restrict__ hb2,
    float* __restrict__ out, int stepi) {
    __shared__ ushort Alds[16384];      // up to 16 rows x 1024 k, fragment layout
    __shared__ float  glds[16 * 96];

    int bx = blockIdx.x;
    int s  = bx >> 6;
    int r2 = bx & 63;
    int mt = r2 >> 3;
    int nb = r2 & 7;
    int t  = stepi - s;
    if (t < 0 || t >= T_STEPS) return;

    int Ks = 512 + 256 * s;
    const ushort* wts = wt + ((s == 0) ? 0 : ((s == 1) ? 393216 : 983040));
    int tid = threadIdx.x;

    // ---- stage A: char part (k in [0,256)), fp32 -> bf16, into fragment layout
    #pragma unroll
    for (int i = 0; i < 4; i++) {
        int q  = tid + 128 * i;        // 0..511 : 16 rows x 32 chunks of 8
        int r  = q >> 5;
        int ko = (q & 31) << 3;
        int n  = mt * 16 + r;
        const float* src = chars + ((size_t)n * T_STEPS + t) * 256 + ko;
        float4 f0 = *(const float4*)src;
        float4 f1 = *(const float4*)(src + 4);
        union { ushort u[8]; uint4 v; } pk;
        pk.u[0] = f2bf(f0.x); pk.u[1] = f2bf(f0.y); pk.u[2] = f2bf(f0.z); pk.u[3] = f2bf(f0.w);
        pk.u[4] = f2bf(f1.x); pk.u[5] = f2bf(f1.y); pk.u[6] = f2bf(f1.z); pk.u[7] = f2bf(f1.w);
        int pos = (ko >> 5) * 512 + (r + 16 * ((ko >> 3) & 3)) * 8;
        *(uint4*)(Alds + pos) = pk.v;
    }
    // ---- stage A: h parts (bf16 ring)
    int nparts = s + 1;
    for (int p = 0; p < nparts; p++) {
        int slot = (p == s) ? ((t - 1) & 3) : (t & 3);
        const ushort* hsrc = ring + ((size_t)p * 4 + slot) * (128 * 256);
        #pragma unroll
        for (int i = 0; i < 4; i++) {
            int q  = tid + 128 * i;
            int r  = q >> 5;
            int ko = (q & 31) << 3;
            int n  = mt * 16 + r;
            uint4 v = *(const uint4*)(hsrc + (size_t)n * 256 + ko);
            int kg  = 256 + p * 256 + ko;
            int pos = (kg >> 5) * 512 + (r + 16 * ((kg >> 3) & 3)) * 8;
            *(uint4*)(Alds + pos) = v;
        }
    }
    __syncthreads();

    // ---- MFMA: [16 x Ks] @ [Ks x 96]; wave w covers cols [nb*96 + w*48, +48)
    int w = tid >> 6, lane = tid & 63;
    int cb = nb * 96 + w * 48;
    f32x4 acc0 = {0.f, 0.f, 0.f, 0.f}, acc1 = {0.f, 0.f, 0.f, 0.f}, acc2 = {0.f, 0.f, 0.f, 0.f};
    const ushort* bp0 = wts + (size_t)(cb + (lane & 15)) * Ks + ((lane >> 4) << 3);
    const ushort* bp1 = bp0 + 16 * (size_t)Ks;
    const ushort* bp2 = bp0 + 32 * (size_t)Ks;
    const ushort* ap  = Alds + lane * 8;
    int nk = Ks >> 5;
    #pragma unroll 8
    for (int ks = 0; ks < nk; ks++) {
        bf16x8 a  = *(const bf16x8*)(ap + ks * 512);
        bf16x8 b0 = *(const bf16x8*)(bp0 + ks * 32);
        bf16x8 b1 = *(const bf16x8*)(bp1 + ks * 32);
        bf16x8 b2 = *(const bf16x8*)(bp2 + ks * 32);
        acc0 = __builtin_amdgcn_mfma_f32_16x16x32_bf16(a, b0, acc0, 0, 0, 0);
        acc1 = __builtin_amdgcn_mfma_f32_16x16x32_bf16(a, b1, acc1, 0, 0, 0);
        acc2 = __builtin_amdgcn_mfma_f32_16x16x32_bf16(a, b2, acc2, 0, 0, 0);
    }

    // ---- gates -> LDS (rows = local sample, cols = 96 permuted gate cols)
    {
        int rbase = (lane >> 4) * 4;
        int c0 = w * 48 + (lane & 15);
        #pragma unroll
        for (int q = 0; q < 4; q++) {
            glds[(rbase + q) * 96 + c0]      = acc0[q];
            glds[(rbase + q) * 96 + c0 + 16] = acc1[q];
            glds[(rbase + q) * 96 + c0 + 32] = acc2[q];
        }
    }
    __syncthreads();

    // ---- gating + h write + head partials
    {
        int sl = tid >> 3;           // local sample 0..15
        int d0 = (tid & 7) * 4;      // 4 h-dims per thread
        int n  = mt * 16 + sl;
        const float* bhh = (s == 0) ? bhh0 : ((s == 1) ? bhh1 : bhh2);
        const float* hw  = (s == 0) ? hw0  : ((s == 1) ? hw1  : hw2);
        const float* hb  = (s == 0) ? hb0  : ((s == 1) ? hb1  : hb2);
        const float* gcp = gc + (size_t)(s * 128 + n) * 768 + nb * 96;
        float y0 = 0.f, y1 = 0.f;
        union { ushort u[4]; uint2 v; } hpk;
        #pragma unroll
        for (int dd = 0; dd < 4; dd++) {
            int d32 = d0 + dd;
            int d   = nb * 32 + d32;
            float rp = glds[sl * 96 + d32]      + gcp[d32];
            float zp = glds[sl * 96 + 32 + d32] + gcp[32 + d32];
            float np = glds[sl * 96 + 64 + d32] + gcp[64 + d32];
            float rg = sigmoidf_(rp);
            float zg = sigmoidf_(zp);
            float ng = tanhf(np + rg * bhh[512 + d]);
            float h  = (1.0f - zg) * ng;
            hpk.u[dd] = f2bf(h);
            y0 += h * hw[d];
            y1 += h * hw[256 + d];
        }
        *(uint2*)(ring + (((size_t)s * 4 + (t & 3)) * 128 + n) * 256 + nb * 32 + d0) = hpk.v;
        y0 += __shfl_xor(y0, 1); y0 += __shfl_xor(y0, 2); y0 += __shfl_xor(y0, 4);
        y1 += __shfl_xor(y1, 1); y1 += __shfl_xor(y1, 2); y1 += __shfl_xor(y1, 4);
        if ((tid & 7) == 0) {
            if (nb == 0) { y0 += hb[0]; y1 += hb[1]; }
            int bb = n >> 3, cc = n & 7;
            atomicAdd(out + (size_t)s * 131072 + (size_t)((bb * 2 + 0) * 8 + cc) * 512 + t, y0);
            atomicAdd(out + (size_t)s * 131072 + (size_t)((bb * 2 + 1) * 8 + cc) * 512 + t, y1);
        }
    }
}

extern "C" void kernel_launch(void* const* d_in, const int* in_sizes, int n_in,
                              void* d_out, int out_size, void* d_ws, size_t ws_size,
                              hipStream_t stream) {
    const float* chars = (const float*)d_in[0];
    const float* sent  = (const float*)d_in[1];
    const float* ctx   = (const float*)d_in[2];
    const float* w0    = (const float*)d_in[3];
    const float* bih0  = (const float*)d_in[4];
    const float* bhh0  = (const float*)d_in[5];
    const float* w1    = (const float*)d_in[6];
    const float* bih1  = (const float*)d_in[7];
    const float* bhh1  = (const float*)d_in[8];
    const float* w2    = (const float*)d_in[9];
    const float* bih2  = (const float*)d_in[10];
    const float* bhh2  = (const float*)d_in[11];
    const float* hw0   = (const float*)d_in[12];
    const float* hb0   = (const float*)d_in[13];
    const float* hw1   = (const float*)d_in[14];
    const float* hb1   = (const float*)d_in[15];
    const float* hw2   = (const float*)d_in[16];
    const float* hb2   = (const float*)d_in[17];

    char* ws = (char*)d_ws;
    ushort* wt   = (ushort*)(ws + WT_OFF);
    float*  gcb  = (float*)(ws + GC_OFF);
    ushort* ring = (ushort*)(ws + RING_OFF);
    float*  out  = (float*)d_out;

    hipMemsetAsync(d_out, 0, (size_t)out_size * sizeof(float), stream);
    hipMemsetAsync(ring, 0, (size_t)3 * 4 * 128 * 256 * 2, stream);

    k_prep<<<6912, 256, 0, stream>>>(w0, w1, w2, wt);
    k_gconst<<<1152, 256, 0, stream>>>(w0, w1, w2, bih0, bih1, bih2,
                                       bhh0, bhh1, bhh2, sent, ctx, gcb);
    for (int i = 0; i < T_STEPS + 2; i++) {
        k_step<<<192, 128, 0, stream>>>(chars, wt, gcb, ring,
                                        bhh0, bhh1, bhh2, hw0, hw1, hw2,
                                        hb0, hb1, hb2, out, i);
    }
}